// Round 5
// baseline (207.744 us; speedup 1.0000x reference)
//
#include <hip/hip_runtime.h>
#include <hip/hip_bf16.h>
#include <cstdint>

typedef __hip_bfloat16 bf16;
typedef __bf16 bf16x8 __attribute__((ext_vector_type(8)));
typedef __bf16 bf16x4 __attribute__((ext_vector_type(4)));
typedef float f32x4 __attribute__((ext_vector_type(4)));
typedef uint32_t u32x4 __attribute__((ext_vector_type(4)));

#define LOG2E 1.4426950408889634f

__device__ __forceinline__ void gload_lds16(const void* g, void* l) {
  __builtin_amdgcn_global_load_lds(
      (const __attribute__((address_space(1))) unsigned int*)g,
      (__attribute__((address_space(3))) unsigned int*)l,
      16, 0, 0);
}

__device__ __forceinline__ uint32_t pack_bf16(float a, float b) {
  const uint32_t ha = (uint32_t)__builtin_bit_cast(uint16_t, (__bf16)a);
  const uint32_t hb = (uint32_t)__builtin_bit_cast(uint16_t, (__bf16)b);
  return ha | (hb << 16);
}

// ---- f32 -> bf16 flat convert, 8 elems/thread ----
__global__ void conv_k(const float* __restrict__ src, bf16* __restrict__ dst, int n) {
  const int i = (blockIdx.x * 256 + threadIdx.x) * 8;
  if (i >= n) return;
  const f32x4 a = *(const f32x4*)(src + i);
  const f32x4 b = *(const f32x4*)(src + i + 4);
  bf16x8 o;
#pragma unroll
  for (int j = 0; j < 4; ++j) { o[j] = (__bf16)a[j]; o[4 + j] = (__bf16)b[j]; }
  *(bf16x8*)(dst + i) = o;
}

// ---- fused 4-matrix transpose+convert: dst[z][c][r] = bf16(src[z][r][c]) ----
__global__ void transpose_conv4(
    const float* __restrict__ wq, const float* __restrict__ wk,
    const float* __restrict__ wv, const float* __restrict__ wo,
    bf16* __restrict__ dqkv, bf16* __restrict__ dout) {
  __shared__ float tile[32][33];
  const int z = blockIdx.z;
  const float* src = (z == 0) ? wq : ((z == 1) ? wk : ((z == 2) ? wv : wo));
  bf16* dst = (z < 3) ? (dqkv + (long)z * 1048576) : dout;
  const int bx = blockIdx.x * 32, by = blockIdx.y * 32;
  const int tx = threadIdx.x;
  for (int j = threadIdx.y; j < 32; j += 8)
    tile[j][tx] = src[(long)(by + j) * 1024 + bx + tx];
  __syncthreads();
  for (int j = threadIdx.y; j < 32; j += 8)
    dst[(long)(bx + j) * 1024 + by + tx] = __float2bfloat16(tile[tx][j]);
}

// ---- m97-style GEMM (128x128): C = A[M,K] * Bt[N,K]^T, bf16, scatter -> QKV ----
__global__ __launch_bounds__(256, 2) void gemm_qkv(
    const bf16* __restrict__ A, const bf16* __restrict__ Bt,
    bf16* __restrict__ Cq, bf16* __restrict__ Ck, bf16* __restrict__ Cv,
    int M, int N, int K) {
  __shared__ __align__(16) bf16 As[128 * 32];
  __shared__ __align__(16) bf16 Bs[128 * 32];

  const int tid = threadIdx.x;
  const int lane = tid & 63;
  const int wave = tid >> 6;
  const int quad = lane >> 4;
  const int l16 = lane & 15;
  const int m0 = blockIdx.y * 128;
  const int n0 = blockIdx.x * 128;
  const int wm = (wave >> 1) * 64;
  const int wn = (wave & 1) * 64;

  const f32x4 zero4 = {0.f, 0.f, 0.f, 0.f};
  f32x4 acc[4][4];
#pragma unroll
  for (int mi = 0; mi < 4; ++mi)
#pragma unroll
    for (int ni = 0; ni < 4; ++ni) acc[mi][ni] = zero4;

  const int sRow = tid >> 2;
  const int sK = (tid & 3) * 8;
  const bf16* Ag = A + (long)(m0 + sRow) * K + sK;
  const bf16* Ag2 = Ag + 64L * K;
  const bf16* Bg = Bt + (long)(n0 + sRow) * K + sK;
  const bf16* Bg2 = Bg + 64L * K;

  for (int k0 = 0; k0 < K; k0 += 32) {
    gload_lds16(Ag + k0, &As[tid * 8]);
    gload_lds16(Ag2 + k0, &As[tid * 8 + 2048]);
    gload_lds16(Bg + k0, &Bs[tid * 8]);
    gload_lds16(Bg2 + k0, &Bs[tid * 8 + 2048]);
    __syncthreads();

    bf16x8 af[4], bfv[4];
#pragma unroll
    for (int mi = 0; mi < 4; ++mi)
      af[mi] = *(const bf16x8*)&As[(wm + mi * 16 + l16) * 32 + quad * 8];
#pragma unroll
    for (int ni = 0; ni < 4; ++ni)
      bfv[ni] = *(const bf16x8*)&Bs[(wn + ni * 16 + l16) * 32 + quad * 8];
#pragma unroll
    for (int mi = 0; mi < 4; ++mi)
#pragma unroll
      for (int ni = 0; ni < 4; ++ni)
        acc[mi][ni] = __builtin_amdgcn_mfma_f32_16x16x32_bf16(af[mi], bfv[ni], acc[mi][ni], 0, 0, 0);
    __syncthreads();
  }

#pragma unroll
  for (int mi = 0; mi < 4; ++mi) {
    const int gmb = m0 + wm + mi * 16 + quad * 4;
#pragma unroll
    for (int ni = 0; ni < 4; ++ni) {
      const int n = n0 + wn + ni * 16 + l16;
      const int which = n >> 10, rem = n & 1023;
      const int h = rem >> 6, hd = rem & 63;
      bf16* dst = (which == 0) ? Cq : ((which == 1) ? Ck : Cv);
#pragma unroll
      for (int r = 0; r < 4; ++r) {
        const int gm = gmb + r;
        const int b = gm >> 11, t = gm & 2047;
        dst[(((long)(b * 16 + h)) * 2048 + t) * 64 + hd] = __float2bfloat16(acc[mi][ni][r]);
      }
    }
  }
}

// ---- output GEMM 64x128 tile (512 blocks): ctx(bf16) @ WtO^T + bias -> f32 ----
// waves_per_eu(4,4): pin allocator to the 128-VGPR budget (no 64-squeeze spill)
__global__ __attribute__((amdgpu_flat_work_group_size(256, 256),
                          amdgpu_waves_per_eu(4, 4))) void gemm_out(
    const bf16* __restrict__ A, const bf16* __restrict__ Bt,
    const float* __restrict__ bias, float* __restrict__ Cout,
    int M, int N, int K) {
  __shared__ __align__(16) bf16 As[64 * 32];
  __shared__ __align__(16) bf16 Bs[128 * 32];

  const int tid = threadIdx.x;
  const int lane = tid & 63;
  const int wave = tid >> 6;
  const int quad = lane >> 4;
  const int l16 = lane & 15;
  const int m0 = blockIdx.y * 64;
  const int n0 = blockIdx.x * 128;
  const int wm = (wave & 1) * 32;
  const int wn = (wave >> 1) * 64;

  const f32x4 zero4 = {0.f, 0.f, 0.f, 0.f};
  f32x4 acc[2][4];
#pragma unroll
  for (int mi = 0; mi < 2; ++mi)
#pragma unroll
    for (int ni = 0; ni < 4; ++ni) acc[mi][ni] = zero4;

  const int sRow = tid >> 2;
  const int sK = (tid & 3) * 8;
  const bf16* Ag = A + (long)(m0 + sRow) * K + sK;
  const bf16* Bg = Bt + (long)(n0 + sRow) * K + sK;
  const bf16* Bg2 = Bg + 64L * K;

  for (int k0 = 0; k0 < K; k0 += 32) {
    gload_lds16(Ag + k0, &As[tid * 8]);
    gload_lds16(Bg + k0, &Bs[tid * 8]);
    gload_lds16(Bg2 + k0, &Bs[tid * 8 + 2048]);
    __syncthreads();

    bf16x8 af[2], bfv[4];
#pragma unroll
    for (int mi = 0; mi < 2; ++mi)
      af[mi] = *(const bf16x8*)&As[(wm + mi * 16 + l16) * 32 + quad * 8];
#pragma unroll
    for (int ni = 0; ni < 4; ++ni)
      bfv[ni] = *(const bf16x8*)&Bs[(wn + ni * 16 + l16) * 32 + quad * 8];
#pragma unroll
    for (int mi = 0; mi < 2; ++mi)
#pragma unroll
      for (int ni = 0; ni < 4; ++ni)
        acc[mi][ni] = __builtin_amdgcn_mfma_f32_16x16x32_bf16(af[mi], bfv[ni], acc[mi][ni], 0, 0, 0);
    __syncthreads();
  }

#pragma unroll
  for (int mi = 0; mi < 2; ++mi) {
    const int gmb = m0 + wm + mi * 16 + quad * 4;
#pragma unroll
    for (int ni = 0; ni < 4; ++ni) {
      const int n = n0 + wn + ni * 16 + l16;
      const float bv = bias[n];
#pragma unroll
      for (int r = 0; r < 4; ++r)
        Cout[(long)(gmb + r) * N + n] = acc[mi][ni][r] + bv;
    }
  }
}

// ---- flash attention v8: v7 + pinned waves_per_eu(4,4) ----
// R0 evidence: launch_bounds(256,3) -> 76 VGPR, zero spill; every (256,4)
// round -> allocator squeezes to exactly 64 VGPR (8-waves/EU tier) and
// spills ~5 regs/lane/iter (WRITE_SIZE 52 MB vs 8.4 legit). LDS caps us at
// 4 blocks/CU anyway, so the squeeze buys nothing. Pinning min=max=4 gives
// the full 512/4 = 128-VGPR budget; live state ~100 fits spill-free.
// grid (32, 32); block 256 (4 waves x 16 q-rows)
__global__ __attribute__((amdgpu_flat_work_group_size(256, 256),
                          amdgpu_waves_per_eu(4, 4))) void attn_kernel(
    const bf16* __restrict__ Q, const bf16* __restrict__ Kg, const bf16* __restrict__ Vg,
    bf16* __restrict__ ctx) {
  constexpr int KSTR = 72, VSTR = 136;
  __shared__ __align__(16) bf16 Ks[128 * KSTR];     // [t][d]
  __shared__ __align__(16) bf16 Vt[64 * VSTR];      // [d][c(k)]

  const int tid = threadIdx.x;
  const int lane = tid & 63;
  const int wave = tid >> 6;
  const int quad = lane >> 4;
  const int l16 = lane & 15;

  // balanced qt swizzle: co-resident blocks {b, b+256, b+512, b+768} get
  // qt in {x, 31-x, x^16, 31-(x^16)} -> per-CU nk sum = 34 for every CU.
  const int x = blockIdx.x;
  const int s4 = blockIdx.y >> 3;
  int qt;
  if (s4 == 0)      qt = x;
  else if (s4 == 1) qt = 31 - x;
  else if (s4 == 2) qt = x ^ 16;
  else              qt = 31 - (x ^ 16);

  const int bh = blockIdx.y;
  const long base = (long)bh * 2048 * 64;
  const int qbase = qt * 64 + wave * 16;
  const int q = qbase + l16;  // this lane's softmax row

  // load Q fragment, prescale by 1/sqrt(64) = 0.125 (exact: power of two)
  bf16x8 qf0 = *(const bf16x8*)(Q + base + (long)(qbase + l16) * 64 + quad * 8);
  bf16x8 qf1 = *(const bf16x8*)(Q + base + (long)(qbase + l16) * 64 + 32 + quad * 8);
#pragma unroll
  for (int j = 0; j < 8; ++j) {
    qf0[j] = (__bf16)((float)qf0[j] * 0.125f);
    qf1[j] = (__bf16)((float)qf1[j] * 0.125f);
  }

  const f32x4 zero4 = {0.f, 0.f, 0.f, 0.f};
  float m_i = -1e30f, l_i = 0.f;
  f32x4 oacc[4];
#pragma unroll
  for (int nb = 0; nb < 4; ++nb) oacc[nb] = zero4;

  const int krow = tid >> 1;
  const int kc32 = (tid & 1) * 32;
  const int vr4 = (tid & 31) * 4;
  const int vd8 = (tid >> 5) * 8;
  // permuted V staging column for k = vr4..vr4+3 (contiguous under c(k))
  const int vb4 = (vr4 >> 4) & 1;
  const int vc4 = (vr4 & ~31) + 8 * (((vr4 >> 2) & 3) ^ vb4) + 4 * vb4;

  const int nk = (qt + 2) >> 1;
  bf16x8 kr[4], vv[4];
  {
    const bf16* kp = Kg + base + (long)krow * 64 + kc32;
#pragma unroll
    for (int i = 0; i < 4; ++i) kr[i] = *(const bf16x8*)(kp + i * 8);
#pragma unroll
    for (int i = 0; i < 4; ++i)
      vv[i] = *(const bf16x8*)(Vg + base + (long)(vr4 + i) * 64 + vd8);
  }

  for (int kt = 0; kt < nk; ++kt) {
    const int k0 = kt * 128;
#pragma unroll
    for (int i = 0; i < 4; ++i)
      *(bf16x8*)&Ks[krow * KSTR + kc32 + i * 8] = kr[i];
#pragma unroll
    for (int j = 0; j < 8; ++j) {
      bf16x4 t;
      t[0] = vv[0][j]; t[1] = vv[1][j]; t[2] = vv[2][j]; t[3] = vv[3][j];
      *(bf16x4*)&Vt[(vd8 + j) * VSTR + vc4] = t;
    }
    __syncthreads();
    if (kt + 1 < nk) {
      const bf16* kp = Kg + base + (long)(k0 + 128 + krow) * 64 + kc32;
#pragma unroll
      for (int i = 0; i < 4; ++i) kr[i] = *(const bf16x8*)(kp + i * 8);
#pragma unroll
      for (int i = 0; i < 4; ++i)
        vv[i] = *(const bf16x8*)(Vg + base + (long)(k0 + 128 + vr4 + i) * 64 + vd8);
    }

    // S^T = mfma(K-frag, Q-frag): lane holds S^T[k=k0+kb*16+quad*4+r][q=l16]
    f32x4 s[8];
    __builtin_amdgcn_s_setprio(1);
#pragma unroll
    for (int kb = 0; kb < 8; ++kb) {
      const bf16x8 kb0 = *(const bf16x8*)&Ks[(kb * 16 + l16) * KSTR + quad * 8];
      const bf16x8 kb1 = *(const bf16x8*)&Ks[(kb * 16 + l16) * KSTR + 32 + quad * 8];
      f32x4 a = zero4;
      a = __builtin_amdgcn_mfma_f32_16x16x32_bf16(kb0, qf0, a, 0, 0, 0);
      a = __builtin_amdgcn_mfma_f32_16x16x32_bf16(kb1, qf1, a, 0, 0, 0);
      s[kb] = a;
    }
    __builtin_amdgcn_s_setprio(0);

    // row max; causal mask only on the tail tile (block-uniform branch)
    float mloc;
    if (kt == nk - 1) {
      const int qg = q - k0 - quad * 4;  // mask: kb*16 + r <= qg
      mloc = -1e30f;
#pragma unroll
      for (int kb = 0; kb < 8; ++kb) {
#pragma unroll
        for (int r = 0; r < 4; ++r) {
          float sv = (kb * 16 + r <= qg) ? s[kb][r] : -1e30f;
          s[kb][r] = sv;
          mloc = fmaxf(mloc, sv);
        }
      }
    } else {
      float mk[8];
#pragma unroll
      for (int kb = 0; kb < 8; ++kb)
        mk[kb] = fmaxf(fmaxf(s[kb][0], s[kb][1]), fmaxf(s[kb][2], s[kb][3]));
      mloc = fmaxf(fmaxf(fmaxf(mk[0], mk[1]), fmaxf(mk[2], mk[3])),
                   fmaxf(fmaxf(mk[4], mk[5]), fmaxf(mk[6], mk[7])));
    }
    mloc = fmaxf(mloc, __shfl_xor(mloc, 16));
    mloc = fmaxf(mloc, __shfl_xor(mloc, 32));

    const float mn = fmaxf(m_i, mloc);
    const float alpha = exp2f((m_i - mn) * LOG2E);
    const float negml = -mn * LOG2E;
    m_i = mn;

    // rescale O (q = quad*4+r rows)
    float alr[4];
#pragma unroll
    for (int r = 0; r < 4; ++r) alr[r] = __shfl(alpha, quad * 4 + r);
#pragma unroll
    for (int nb = 0; nb < 4; ++nb)
#pragma unroll
      for (int r = 0; r < 4; ++r) oacc[nb][r] *= alr[r];

    // phase 2: exp + pack + exchange -- consumes ALL of s[8] (32 f32) into
    // paw[4] (16 u32) BEFORE any PV MFMA issues (keeps peak pressure low)
    float rsum = 0.f;
    u32x4 paw[4];
#pragma unroll
    for (int kk = 0; kk < 4; ++kk) {
      const float p0 = exp2f(fmaf(s[2 * kk][0], LOG2E, negml));
      const float p1 = exp2f(fmaf(s[2 * kk][1], LOG2E, negml));
      const float p2 = exp2f(fmaf(s[2 * kk][2], LOG2E, negml));
      const float p3 = exp2f(fmaf(s[2 * kk][3], LOG2E, negml));
      const float p4 = exp2f(fmaf(s[2 * kk + 1][0], LOG2E, negml));
      const float p5 = exp2f(fmaf(s[2 * kk + 1][1], LOG2E, negml));
      const float p6 = exp2f(fmaf(s[2 * kk + 1][2], LOG2E, negml));
      const float p7 = exp2f(fmaf(s[2 * kk + 1][3], LOG2E, negml));
      rsum += ((p0 + p1) + (p2 + p3)) + ((p4 + p5) + (p6 + p7));
      u32x4 w;
      w[0] = pack_bf16(p0, p1);
      w[1] = pack_bf16(p2, p3);
      w[2] = (uint32_t)__shfl_xor((int)pack_bf16(p4, p5), 16);
      w[3] = (uint32_t)__shfl_xor((int)pack_bf16(p6, p7), 16);
      paw[kk] = w;
    }
    rsum += __shfl_xor(rsum, 16);
    rsum += __shfl_xor(rsum, 32);
    l_i = l_i * alpha + rsum;

    // phase 3: pure-MFMA PV cluster (V columns pre-permuted in Vt layout)
    __builtin_amdgcn_s_setprio(1);
#pragma unroll
    for (int kk = 0; kk < 4; ++kk) {
      const bf16x8 pa = __builtin_bit_cast(bf16x8, paw[kk]);
#pragma unroll
      for (int nb2 = 0; nb2 < 4; ++nb2) {
        const bf16x8 vb = *(const bf16x8*)&Vt[(nb2 * 16 + l16) * VSTR + kk * 32 + quad * 8];
        oacc[nb2] = __builtin_amdgcn_mfma_f32_16x16x32_bf16(pa, vb, oacc[nb2], 0, 0, 0);
      }
    }
    __builtin_amdgcn_s_setprio(0);
    __syncthreads();
  }

  // epilogue
  const int b = bh >> 4, h = bh & 15;
  float linv[4];
#pragma unroll
  for (int r = 0; r < 4; ++r) linv[r] = 1.0f / __shfl(l_i, quad * 4 + r);
#pragma unroll
  for (int r = 0; r < 4; ++r) {
    const int t = qbase + quad * 4 + r;
#pragma unroll
    for (int nb2 = 0; nb2 < 4; ++nb2) {
      const int d = h * 64 + nb2 * 16 + l16;
      ctx[((long)b * 2048 + t) * 1024 + d] = __float2bfloat16(oacc[nb2][r] * linv[r]);
    }
  }
}

extern "C" void kernel_launch(void* const* d_in, const int* in_sizes, int n_in,
                              void* d_out, int out_size, void* d_ws, size_t ws_size,
                              hipStream_t stream) {
  const float* x  = (const float*)d_in[0];
  const float* wq = (const float*)d_in[1];
  const float* wk = (const float*)d_in[2];
  const float* wv = (const float*)d_in[3];
  const float* wo = (const float*)d_in[4];
  const float* bo = (const float*)d_in[5];
  float* out = (float*)d_out;

  bf16* Wtqkv = (bf16*)d_ws;            // 3 * 1048576
  bf16* Wto   = Wtqkv + 3145728;        // 1048576
  bf16* xb    = Wto + 1048576;          // 4194304 (reused as Cx)
  bf16* Qb    = xb + 4194304;
  bf16* Kb    = Qb + 4194304;
  bf16* Vb    = Kb + 4194304;
  bf16* Cx    = xb;

  hipLaunchKernelGGL(conv_k, dim3(2048), dim3(256), 0, stream, x, xb, 4194304);
  hipLaunchKernelGGL(transpose_conv4, dim3(32, 32, 4), dim3(32, 8), 0, stream,
                     wq, wk, wv, wo, Wtqkv, Wto);

  hipLaunchKernelGGL(gemm_qkv, dim3(24, 32), dim3(256), 0, stream,
                     xb, Wtqkv, Qb, Kb, Vb, 4096, 3072, 1024);

  hipLaunchKernelGGL(attn_kernel, dim3(32, 32), dim3(256), 0, stream, Qb, Kb, Vb, Cx);

  hipLaunchKernelGGL(gemm_out, dim3(8, 64), dim3(256), 0, stream,
                     Cx, Wto, bo, out, 4096, 1024, 1024);
}

// Round 6
// 204.276 us; speedup vs baseline: 1.0170x; 1.0170x over previous
//
#include <hip/hip_runtime.h>
#include <hip/hip_bf16.h>
#include <cstdint>

typedef __hip_bfloat16 bf16;
typedef __bf16 bf16x8 __attribute__((ext_vector_type(8)));
typedef __bf16 bf16x4 __attribute__((ext_vector_type(4)));
typedef float f32x4 __attribute__((ext_vector_type(4)));
typedef uint32_t u32x4 __attribute__((ext_vector_type(4)));

#define LOG2E 1.4426950408889634f

__device__ __forceinline__ void gload_lds16(const void* g, void* l) {
  __builtin_amdgcn_global_load_lds(
      (const __attribute__((address_space(1))) unsigned int*)g,
      (__attribute__((address_space(3))) unsigned int*)l,
      16, 0, 0);
}

__device__ __forceinline__ uint32_t pack_bf16(float a, float b) {
  const uint32_t ha = (uint32_t)__builtin_bit_cast(uint16_t, (__bf16)a);
  const uint32_t hb = (uint32_t)__builtin_bit_cast(uint16_t, (__bf16)b);
  return ha | (hb << 16);
}

// ---- f32 -> bf16 flat convert, 8 elems/thread ----
__global__ void conv_k(const float* __restrict__ src, bf16* __restrict__ dst, int n) {
  const int i = (blockIdx.x * 256 + threadIdx.x) * 8;
  if (i >= n) return;
  const f32x4 a = *(const f32x4*)(src + i);
  const f32x4 b = *(const f32x4*)(src + i + 4);
  bf16x8 o;
#pragma unroll
  for (int j = 0; j < 4; ++j) { o[j] = (__bf16)a[j]; o[4 + j] = (__bf16)b[j]; }
  *(bf16x8*)(dst + i) = o;
}

// ---- fused 4-matrix transpose+convert: dst[z][c][r] = bf16(src[z][r][c]) ----
__global__ void transpose_conv4(
    const float* __restrict__ wq, const float* __restrict__ wk,
    const float* __restrict__ wv, const float* __restrict__ wo,
    bf16* __restrict__ dqkv, bf16* __restrict__ dout) {
  __shared__ float tile[32][33];
  const int z = blockIdx.z;
  const float* src = (z == 0) ? wq : ((z == 1) ? wk : ((z == 2) ? wv : wo));
  bf16* dst = (z < 3) ? (dqkv + (long)z * 1048576) : dout;
  const int bx = blockIdx.x * 32, by = blockIdx.y * 32;
  const int tx = threadIdx.x;
  for (int j = threadIdx.y; j < 32; j += 8)
    tile[j][tx] = src[(long)(by + j) * 1024 + bx + tx];
  __syncthreads();
  for (int j = threadIdx.y; j < 32; j += 8)
    dst[(long)(bx + j) * 1024 + by + tx] = __float2bfloat16(tile[tx][j]);
}

// ---- m97-style GEMM (128x128): C = A[M,K] * Bt[N,K]^T, bf16, scatter -> QKV ----
__global__ __launch_bounds__(256, 2) void gemm_qkv(
    const bf16* __restrict__ A, const bf16* __restrict__ Bt,
    bf16* __restrict__ Cq, bf16* __restrict__ Ck, bf16* __restrict__ Cv,
    int M, int N, int K) {
  __shared__ __align__(16) bf16 As[128 * 32];
  __shared__ __align__(16) bf16 Bs[128 * 32];

  const int tid = threadIdx.x;
  const int lane = tid & 63;
  const int wave = tid >> 6;
  const int quad = lane >> 4;
  const int l16 = lane & 15;
  const int m0 = blockIdx.y * 128;
  const int n0 = blockIdx.x * 128;
  const int wm = (wave >> 1) * 64;
  const int wn = (wave & 1) * 64;

  const f32x4 zero4 = {0.f, 0.f, 0.f, 0.f};
  f32x4 acc[4][4];
#pragma unroll
  for (int mi = 0; mi < 4; ++mi)
#pragma unroll
    for (int ni = 0; ni < 4; ++ni) acc[mi][ni] = zero4;

  const int sRow = tid >> 2;
  const int sK = (tid & 3) * 8;
  const bf16* Ag = A + (long)(m0 + sRow) * K + sK;
  const bf16* Ag2 = Ag + 64L * K;
  const bf16* Bg = Bt + (long)(n0 + sRow) * K + sK;
  const bf16* Bg2 = Bg + 64L * K;

  for (int k0 = 0; k0 < K; k0 += 32) {
    gload_lds16(Ag + k0, &As[tid * 8]);
    gload_lds16(Ag2 + k0, &As[tid * 8 + 2048]);
    gload_lds16(Bg + k0, &Bs[tid * 8]);
    gload_lds16(Bg2 + k0, &Bs[tid * 8 + 2048]);
    __syncthreads();

    bf16x8 af[4], bfv[4];
#pragma unroll
    for (int mi = 0; mi < 4; ++mi)
      af[mi] = *(const bf16x8*)&As[(wm + mi * 16 + l16) * 32 + quad * 8];
#pragma unroll
    for (int ni = 0; ni < 4; ++ni)
      bfv[ni] = *(const bf16x8*)&Bs[(wn + ni * 16 + l16) * 32 + quad * 8];
#pragma unroll
    for (int mi = 0; mi < 4; ++mi)
#pragma unroll
      for (int ni = 0; ni < 4; ++ni)
        acc[mi][ni] = __builtin_amdgcn_mfma_f32_16x16x32_bf16(af[mi], bfv[ni], acc[mi][ni], 0, 0, 0);
    __syncthreads();
  }

#pragma unroll
  for (int mi = 0; mi < 4; ++mi) {
    const int gmb = m0 + wm + mi * 16 + quad * 4;
#pragma unroll
    for (int ni = 0; ni < 4; ++ni) {
      const int n = n0 + wn + ni * 16 + l16;
      const int which = n >> 10, rem = n & 1023;
      const int h = rem >> 6, hd = rem & 63;
      bf16* dst = (which == 0) ? Cq : ((which == 1) ? Ck : Cv);
#pragma unroll
      for (int r = 0; r < 4; ++r) {
        const int gm = gmb + r;
        const int b = gm >> 11, t = gm & 2047;
        dst[(((long)(b * 16 + h)) * 2048 + t) * 64 + hd] = __float2bfloat16(acc[mi][ni][r]);
      }
    }
  }
}

// ---- output GEMM 64x128 tile (512 blocks): ctx(bf16) @ WtO^T + bias -> f32 ----
__global__ __launch_bounds__(256, 4) void gemm_out(
    const bf16* __restrict__ A, const bf16* __restrict__ Bt,
    const float* __restrict__ bias, float* __restrict__ Cout,
    int M, int N, int K) {
  __shared__ __align__(16) bf16 As[64 * 32];
  __shared__ __align__(16) bf16 Bs[128 * 32];

  const int tid = threadIdx.x;
  const int lane = tid & 63;
  const int wave = tid >> 6;
  const int quad = lane >> 4;
  const int l16 = lane & 15;
  const int m0 = blockIdx.y * 64;
  const int n0 = blockIdx.x * 128;
  const int wm = (wave & 1) * 32;
  const int wn = (wave >> 1) * 64;

  const f32x4 zero4 = {0.f, 0.f, 0.f, 0.f};
  f32x4 acc[2][4];
#pragma unroll
  for (int mi = 0; mi < 2; ++mi)
#pragma unroll
    for (int ni = 0; ni < 4; ++ni) acc[mi][ni] = zero4;

  const int sRow = tid >> 2;
  const int sK = (tid & 3) * 8;
  const bf16* Ag = A + (long)(m0 + sRow) * K + sK;
  const bf16* Bg = Bt + (long)(n0 + sRow) * K + sK;
  const bf16* Bg2 = Bg + 64L * K;

  for (int k0 = 0; k0 < K; k0 += 32) {
    gload_lds16(Ag + k0, &As[tid * 8]);
    gload_lds16(Bg + k0, &Bs[tid * 8]);
    gload_lds16(Bg2 + k0, &Bs[tid * 8 + 2048]);
    __syncthreads();

    bf16x8 af[2], bfv[4];
#pragma unroll
    for (int mi = 0; mi < 2; ++mi)
      af[mi] = *(const bf16x8*)&As[(wm + mi * 16 + l16) * 32 + quad * 8];
#pragma unroll
    for (int ni = 0; ni < 4; ++ni)
      bfv[ni] = *(const bf16x8*)&Bs[(wn + ni * 16 + l16) * 32 + quad * 8];
#pragma unroll
    for (int mi = 0; mi < 2; ++mi)
#pragma unroll
      for (int ni = 0; ni < 4; ++ni)
        acc[mi][ni] = __builtin_amdgcn_mfma_f32_16x16x32_bf16(af[mi], bfv[ni], acc[mi][ni], 0, 0, 0);
    __syncthreads();
  }

#pragma unroll
  for (int mi = 0; mi < 2; ++mi) {
    const int gmb = m0 + wm + mi * 16 + quad * 4;
#pragma unroll
    for (int ni = 0; ni < 4; ++ni) {
      const int n = n0 + wn + ni * 16 + l16;
      const float bv = bias[n];
#pragma unroll
      for (int r = 0; r < 4; ++r)
        Cout[(long)(gmb + r) * N + n] = acc[mi][ni][r] + bv;
    }
  }
}

// ---- flash attention v9: v8 logic with __launch_bounds__(256, 3) ----
// Evidence table (R0-R5): any min=4 occupancy directive (launch_bounds or
// waves_per_eu) pins the allocator to the 64-VGPR tier -> ~45 MB/dispatch
// scratch round-trip (peak live state ~100 VGPR can't fit 64). The one
// min=3 build (R0) allocated 76 VGPR with ZERO spill. Runtime occupancy is
// set by actual VGPR (<=128 keeps 4 blocks/CU) + LDS (35.8 KB -> 4/CU), so
// min=3 does not itself cost occupancy.
// grid (32, 32); block 256 (4 waves x 16 q-rows)
__global__ __launch_bounds__(256, 3) void attn_kernel(
    const bf16* __restrict__ Q, const bf16* __restrict__ Kg, const bf16* __restrict__ Vg,
    bf16* __restrict__ ctx) {
  constexpr int KSTR = 72, VSTR = 136;
  __shared__ __align__(16) bf16 Ks[128 * KSTR];     // [t][d]
  __shared__ __align__(16) bf16 Vt[64 * VSTR];      // [d][c(k)]

  const int tid = threadIdx.x;
  const int lane = tid & 63;
  const int wave = tid >> 6;
  const int quad = lane >> 4;
  const int l16 = lane & 15;

  // balanced qt swizzle: co-resident blocks {b, b+256, b+512, b+768} get
  // qt in {x, 31-x, x^16, 31-(x^16)} -> per-CU nk sum = 34 for every CU.
  const int x = blockIdx.x;
  const int s4 = blockIdx.y >> 3;
  int qt;
  if (s4 == 0)      qt = x;
  else if (s4 == 1) qt = 31 - x;
  else if (s4 == 2) qt = x ^ 16;
  else              qt = 31 - (x ^ 16);

  const int bh = blockIdx.y;
  const long base = (long)bh * 2048 * 64;
  const int qbase = qt * 64 + wave * 16;
  const int q = qbase + l16;  // this lane's softmax row

  // load Q fragment, prescale by 1/sqrt(64) = 0.125 (exact: power of two)
  bf16x8 qf0 = *(const bf16x8*)(Q + base + (long)(qbase + l16) * 64 + quad * 8);
  bf16x8 qf1 = *(const bf16x8*)(Q + base + (long)(qbase + l16) * 64 + 32 + quad * 8);
#pragma unroll
  for (int j = 0; j < 8; ++j) {
    qf0[j] = (__bf16)((float)qf0[j] * 0.125f);
    qf1[j] = (__bf16)((float)qf1[j] * 0.125f);
  }

  const f32x4 zero4 = {0.f, 0.f, 0.f, 0.f};
  float m_i = -1e30f, l_i = 0.f;
  f32x4 oacc[4];
#pragma unroll
  for (int nb = 0; nb < 4; ++nb) oacc[nb] = zero4;

  const int krow = tid >> 1;
  const int kc32 = (tid & 1) * 32;
  const int vr4 = (tid & 31) * 4;
  const int vd8 = (tid >> 5) * 8;
  // permuted V staging column for k = vr4..vr4+3 (contiguous under c(k))
  const int vb4 = (vr4 >> 4) & 1;
  const int vc4 = (vr4 & ~31) + 8 * (((vr4 >> 2) & 3) ^ vb4) + 4 * vb4;

  const int nk = (qt + 2) >> 1;
  bf16x8 kr[4], vv[4];
  {
    const bf16* kp = Kg + base + (long)krow * 64 + kc32;
#pragma unroll
    for (int i = 0; i < 4; ++i) kr[i] = *(const bf16x8*)(kp + i * 8);
#pragma unroll
    for (int i = 0; i < 4; ++i)
      vv[i] = *(const bf16x8*)(Vg + base + (long)(vr4 + i) * 64 + vd8);
  }

  for (int kt = 0; kt < nk; ++kt) {
    const int k0 = kt * 128;
#pragma unroll
    for (int i = 0; i < 4; ++i)
      *(bf16x8*)&Ks[krow * KSTR + kc32 + i * 8] = kr[i];
#pragma unroll
    for (int j = 0; j < 8; ++j) {
      bf16x4 t;
      t[0] = vv[0][j]; t[1] = vv[1][j]; t[2] = vv[2][j]; t[3] = vv[3][j];
      *(bf16x4*)&Vt[(vd8 + j) * VSTR + vc4] = t;
    }
    __syncthreads();
    if (kt + 1 < nk) {
      const bf16* kp = Kg + base + (long)(k0 + 128 + krow) * 64 + kc32;
#pragma unroll
      for (int i = 0; i < 4; ++i) kr[i] = *(const bf16x8*)(kp + i * 8);
#pragma unroll
      for (int i = 0; i < 4; ++i)
        vv[i] = *(const bf16x8*)(Vg + base + (long)(k0 + 128 + vr4 + i) * 64 + vd8);
    }

    // S^T = mfma(K-frag, Q-frag): lane holds S^T[k=k0+kb*16+quad*4+r][q=l16]
    f32x4 s[8];
    __builtin_amdgcn_s_setprio(1);
#pragma unroll
    for (int kb = 0; kb < 8; ++kb) {
      const bf16x8 kb0 = *(const bf16x8*)&Ks[(kb * 16 + l16) * KSTR + quad * 8];
      const bf16x8 kb1 = *(const bf16x8*)&Ks[(kb * 16 + l16) * KSTR + 32 + quad * 8];
      f32x4 a = zero4;
      a = __builtin_amdgcn_mfma_f32_16x16x32_bf16(kb0, qf0, a, 0, 0, 0);
      a = __builtin_amdgcn_mfma_f32_16x16x32_bf16(kb1, qf1, a, 0, 0, 0);
      s[kb] = a;
    }
    __builtin_amdgcn_s_setprio(0);

    // row max; causal mask only on the tail tile (block-uniform branch)
    float mloc;
    if (kt == nk - 1) {
      const int qg = q - k0 - quad * 4;  // mask: kb*16 + r <= qg
      mloc = -1e30f;
#pragma unroll
      for (int kb = 0; kb < 8; ++kb) {
#pragma unroll
        for (int r = 0; r < 4; ++r) {
          float sv = (kb * 16 + r <= qg) ? s[kb][r] : -1e30f;
          s[kb][r] = sv;
          mloc = fmaxf(mloc, sv);
        }
      }
    } else {
      float mk[8];
#pragma unroll
      for (int kb = 0; kb < 8; ++kb)
        mk[kb] = fmaxf(fmaxf(s[kb][0], s[kb][1]), fmaxf(s[kb][2], s[kb][3]));
      mloc = fmaxf(fmaxf(fmaxf(mk[0], mk[1]), fmaxf(mk[2], mk[3])),
                   fmaxf(fmaxf(mk[4], mk[5]), fmaxf(mk[6], mk[7])));
    }
    mloc = fmaxf(mloc, __shfl_xor(mloc, 16));
    mloc = fmaxf(mloc, __shfl_xor(mloc, 32));

    const float mn = fmaxf(m_i, mloc);
    const float alpha = exp2f((m_i - mn) * LOG2E);
    const float negml = -mn * LOG2E;
    m_i = mn;

    // rescale O (q = quad*4+r rows)
    float alr[4];
#pragma unroll
    for (int r = 0; r < 4; ++r) alr[r] = __shfl(alpha, quad * 4 + r);
#pragma unroll
    for (int nb = 0; nb < 4; ++nb)
#pragma unroll
      for (int r = 0; r < 4; ++r) oacc[nb][r] *= alr[r];

    // phase 2: exp + pack + exchange -- consumes ALL of s[8] (32 f32) into
    // paw[4] (16 u32) BEFORE any PV MFMA issues (keeps peak pressure low)
    float rsum = 0.f;
    u32x4 paw[4];
#pragma unroll
    for (int kk = 0; kk < 4; ++kk) {
      const float p0 = exp2f(fmaf(s[2 * kk][0], LOG2E, negml));
      const float p1 = exp2f(fmaf(s[2 * kk][1], LOG2E, negml));
      const float p2 = exp2f(fmaf(s[2 * kk][2], LOG2E, negml));
      const float p3 = exp2f(fmaf(s[2 * kk][3], LOG2E, negml));
      const float p4 = exp2f(fmaf(s[2 * kk + 1][0], LOG2E, negml));
      const float p5 = exp2f(fmaf(s[2 * kk + 1][1], LOG2E, negml));
      const float p6 = exp2f(fmaf(s[2 * kk + 1][2], LOG2E, negml));
      const float p7 = exp2f(fmaf(s[2 * kk + 1][3], LOG2E, negml));
      rsum += ((p0 + p1) + (p2 + p3)) + ((p4 + p5) + (p6 + p7));
      u32x4 w;
      w[0] = pack_bf16(p0, p1);
      w[1] = pack_bf16(p2, p3);
      w[2] = (uint32_t)__shfl_xor((int)pack_bf16(p4, p5), 16);
      w[3] = (uint32_t)__shfl_xor((int)pack_bf16(p6, p7), 16);
      paw[kk] = w;
    }
    rsum += __shfl_xor(rsum, 16);
    rsum += __shfl_xor(rsum, 32);
    l_i = l_i * alpha + rsum;

    // phase 3: pure-MFMA PV cluster (V columns pre-permuted in Vt layout)
    __builtin_amdgcn_s_setprio(1);
#pragma unroll
    for (int kk = 0; kk < 4; ++kk) {
      const bf16x8 pa = __builtin_bit_cast(bf16x8, paw[kk]);
#pragma unroll
      for (int nb2 = 0; nb2 < 4; ++nb2) {
        const bf16x8 vb = *(const bf16x8*)&Vt[(nb2 * 16 + l16) * VSTR + kk * 32 + quad * 8];
        oacc[nb2] = __builtin_amdgcn_mfma_f32_16x16x32_bf16(pa, vb, oacc[nb2], 0, 0, 0);
      }
    }
    __builtin_amdgcn_s_setprio(0);
    __syncthreads();
  }

  // epilogue
  const int b = bh >> 4, h = bh & 15;
  float linv[4];
#pragma unroll
  for (int r = 0; r < 4; ++r) linv[r] = 1.0f / __shfl(l_i, quad * 4 + r);
#pragma unroll
  for (int r = 0; r < 4; ++r) {
    const int t = qbase + quad * 4 + r;
#pragma unroll
    for (int nb2 = 0; nb2 < 4; ++nb2) {
      const int d = h * 64 + nb2 * 16 + l16;
      ctx[((long)b * 2048 + t) * 1024 + d] = __float2bfloat16(oacc[nb2][r] * linv[r]);
    }
  }
}

extern "C" void kernel_launch(void* const* d_in, const int* in_sizes, int n_in,
                              void* d_out, int out_size, void* d_ws, size_t ws_size,
                              hipStream_t stream) {
  const float* x  = (const float*)d_in[0];
  const float* wq = (const float*)d_in[1];
  const float* wk = (const float*)d_in[2];
  const float* wv = (const float*)d_in[3];
  const float* wo = (const float*)d_in[4];
  const float* bo = (const float*)d_in[5];
  float* out = (float*)d_out;

  bf16* Wtqkv = (bf16*)d_ws;            // 3 * 1048576
  bf16* Wto   = Wtqkv + 3145728;        // 1048576
  bf16* xb    = Wto + 1048576;          // 4194304 (reused as Cx)
  bf16* Qb    = xb + 4194304;
  bf16* Kb    = Qb + 4194304;
  bf16* Vb    = Kb + 4194304;
  bf16* Cx    = xb;

  hipLaunchKernelGGL(conv_k, dim3(2048), dim3(256), 0, stream, x, xb, 4194304);
  hipLaunchKernelGGL(transpose_conv4, dim3(32, 32, 4), dim3(32, 8), 0, stream,
                     wq, wk, wv, wo, Wtqkv, Wto);

  hipLaunchKernelGGL(gemm_qkv, dim3(24, 32), dim3(256), 0, stream,
                     xb, Wtqkv, Qb, Kb, Vb, 4096, 3072, 1024);

  hipLaunchKernelGGL(attn_kernel, dim3(32, 32), dim3(256), 0, stream, Qb, Kb, Vb, Cx);

  hipLaunchKernelGGL(gemm_out, dim3(8, 64), dim3(256), 0, stream,
                     Cx, Wto, bo, out, 4096, 1024, 1024);
}